// Round 1
// baseline (177.432 us; speedup 1.0000x reference)
//
#include <hip/hip_runtime.h>
#include <math.h>

#define KOLD 128
#define KNEW 100

// Precompute, for each of the 101 new edges, which old bin it falls in and the
// fractional position within that bin. Row-independent -> tiny 1-block kernel.
__global__ void edge_map_k(const float* __restrict__ oe,   // 129 old edges
                           const float* __restrict__ ne,   // 101 new edges
                           int* __restrict__ eidx,         // 101
                           float* __restrict__ et) {       // 101
    int k = threadIdx.x;
    if (k > KNEW) return;
    float e = ne[k];
    int i = 0;
    for (int m = 1; m < KOLD; ++m)
        if (oe[m] <= e) i = m;
    float a = oe[i], b = oe[i + 1];
    float t = (e - a) / (b - a);
    t = fminf(fmaxf(t, 0.f), 1.f);
    eidx[k] = i;
    et[k] = t;
}

// One wave (64 lanes) per row. Lane l holds logits[2l], logits[2l+1].
__launch_bounds__(256)
__global__ void rebin_k(const float* __restrict__ logits,
                        const int* __restrict__ eidx,
                        const float* __restrict__ et,
                        float* __restrict__ out, int nrows) {
    const int lane = threadIdx.x & 63;
    const int row = blockIdx.x * 4 + (threadIdx.x >> 6);
    if (row >= nrows) return;

    const float2 x = *reinterpret_cast<const float2*>(
        logits + (size_t)row * KOLD + lane * 2);

    // wave max (softmax stabilization)
    float m = fmaxf(x.x, x.y);
#pragma unroll
    for (int off = 32; off; off >>= 1)
        m = fmaxf(m, __shfl_xor(m, off, 64));

    float e0 = __expf(x.x - m);
    float e1 = __expf(x.y - m);
    float sl = e0 + e1;

    // inclusive wave scan of per-lane pair-sums
    float scan = sl;
#pragma unroll
    for (int off = 1; off < 64; off <<= 1) {
        float v = __shfl_up(scan, off, 64);
        if (lane >= off) scan += v;
    }
    const float S    = __shfl(scan, 63, 64);   // total (unnormalized)
    const float invS = 1.0f / S;
    const float P0   = scan - sl;              // excl. prefix before elem 2*lane

    // CDF at new-edge k, for k = lane and k = lane + 64
    const int  kB   = lane + 64;
    const int  iA   = eidx[lane];
    const float tA  = et[lane];
    const bool hasB = (kB <= KNEW);            // lane <= 36
    const int  iB   = hasB ? eidx[kB] : 0;
    const float tB  = hasB ? et[kB]   : 0.f;

    const int sA = iA >> 1, sB = iB >> 1;
    float pA  = __shfl(P0, sA, 64);
    float qA0 = __shfl(e0, sA, 64);
    float qA1 = __shfl(e1, sA, 64);
    float pB  = __shfl(P0, sB, 64);
    float qB0 = __shfl(e0, sB, 64);
    float qB1 = __shfl(e1, sB, 64);

    float PA = (iA & 1) ? (pA + qA0) : pA;
    float eA = (iA & 1) ? qA1 : qA0;
    float PB = (iB & 1) ? (pB + qB0) : pB;
    float eB = (iB & 1) ? qB1 : qB0;

    float F0 = (PA + eA * tA) * invS;          // F(new_edge[lane])
    float F1 = (PB + eB * tB) * invS;          // F(new_edge[lane+64])

    float F0n = __shfl_down(F0, 1, 64);        // F(new_edge[lane+1])
    float F1n = __shfl_down(F1, 1, 64);        // F(new_edge[lane+65])
    float F64 = __shfl(F1, 0, 64);             // F(new_edge[64])

    const float tiny = 1.1754943508222875e-38f;
    float* orow = out + (size_t)row * KNEW;

    float nA = (lane == 63) ? F64 : F0n;
    orow[lane] = __logf(fmaxf(nA - F0, 0.f) + tiny);

    if (lane < KNEW - 64) {                    // lanes 0..35 -> j = 64..99
        orow[64 + lane] = __logf(fmaxf(F1n - F1, 0.f) + tiny);
    }
}

extern "C" void kernel_launch(void* const* d_in, const int* in_sizes, int n_in,
                              void* d_out, int out_size, void* d_ws, size_t ws_size,
                              hipStream_t stream) {
    const float* logits = (const float*)d_in[0];
    const float* oe     = (const float*)d_in[1];
    const float* ne     = (const float*)d_in[2];
    float* out          = (float*)d_out;
    const int nrows     = in_sizes[0] / KOLD;

    int*   eidx = (int*)d_ws;
    float* et   = (float*)((char*)d_ws + 512);

    edge_map_k<<<1, 128, 0, stream>>>(oe, ne, eidx, et);

    const int blocks = (nrows + 3) / 4;   // 4 rows (waves) per 256-thread block
    rebin_k<<<blocks, 256, 0, stream>>>(logits, eidx, et, out, nrows);
}